// Round 4
// baseline (112.930 us; speedup 1.0000x reference)
//
#include <hip/hip_runtime.h>

// EllipticalShapeLoss: streaming pass computes raw moments M_pq = sum_mask y^p x^q
// (p+q<=4) per batch. Row-per-wave lane-contiguous nontemporal float4 loads with a
// 2-row software pipeline; per-block double partials to d_ws (no memset, no
// atomics, deterministic); parallel finalize kernel does the covariance algebra.

constexpr int BATCH = 32;
constexpr int H = 1024;
constexpr int W = 1024;
constexpr int NPIX = H * W;
constexpr int NMOM = 15;
constexpr int TPB = 256;                           // 4 waves per block
constexpr int WAVES_PER_BLOCK = TPB / 64;
constexpr int BLOCKS_PER_BATCH = 32;
constexpr int WAVES_PER_BATCH = BLOCKS_PER_BATCH * WAVES_PER_BLOCK;  // 128
constexpr int ROWS_PER_WAVE = H / WAVES_PER_BATCH;                   // 8
constexpr int NBLOCKS = BATCH * BLOCKS_PER_BATCH;                    // 1024

typedef float f32x4 __attribute__((ext_vector_type(4)));

// moment index -> (p,q):  0:(0,0) 1:(1,0) 2:(0,1) 3:(2,0) 4:(1,1) 5:(0,2)
// 6:(3,0) 7:(2,1) 8:(1,2) 9:(0,3) 10:(4,0) 11:(3,1) 12:(2,2) 13:(1,3) 14:(0,4)

__device__ __forceinline__ void load_row(const f32x4* __restrict__ r0,
                                         const f32x4* __restrict__ r1,
                                         int lane, f32x4* a, f32x4* b) {
#pragma unroll
  for (int j = 0; j < 4; ++j) a[j] = __builtin_nontemporal_load(r0 + j * 64 + lane);
#pragma unroll
  for (int j = 0; j < 4; ++j) b[j] = __builtin_nontemporal_load(r1 + j * 64 + lane);
}

__device__ __forceinline__ void compute_row(const f32x4* a, const f32x4* b, int y,
                                            const double X, const double X2,
                                            const double X3, const double X4,
                                            double* acc) {
  // masked power sums over v = 256j + t (compile-time literals)
  unsigned s0 = 0, s1 = 0, s2 = 0;
  unsigned long long s3 = 0, s4 = 0;
#pragma unroll
  for (int j = 0; j < 4; ++j) {
#pragma unroll
    for (int t = 0; t < 4; ++t) {
      const unsigned long long v = (unsigned long long)(256 * j + t);
      const bool m = b[j][t] > a[j][t];            // argmax==FG (ties -> class 0)
      s0 += m ? 1u : 0u;
      s1 += m ? (unsigned)v : 0u;
      s2 += m ? (unsigned)(v * v) : 0u;
      s3 += m ? v * v * v : 0ull;
      s4 += m ? v * v * v * v : 0ull;
    }
  }
  // binomial shift by X: T_q = sum_mask x^q over this thread's row pixels
  const double S0 = s0, S1 = s1, S2 = s2, S3 = (double)s3, S4 = (double)s4;
  const double T0 = S0;
  const double T1 = X * S0 + S1;
  const double T2 = X2 * S0 + 2.0 * X * S1 + S2;
  const double T3 = X3 * S0 + 3.0 * X2 * S1 + 3.0 * X * S2 + S3;
  const double T4 = X4 * S0 + 4.0 * X3 * S1 + 6.0 * X2 * S2 + 4.0 * X * S3 + S4;
  const double Y = (double)y;
  const double Y2 = Y * Y, Y3 = Y2 * Y, Y4 = Y2 * Y2;
  acc[0] += T0;
  acc[1] += Y * T0;
  acc[2] += T1;
  acc[3] += Y2 * T0;
  acc[4] += Y * T1;
  acc[5] += T2;
  acc[6] += Y3 * T0;
  acc[7] += Y2 * T1;
  acc[8] += Y * T2;
  acc[9] += T3;
  acc[10] += Y4 * T0;
  acc[11] += Y3 * T1;
  acc[12] += Y2 * T2;
  acc[13] += Y * T3;
  acc[14] += T4;
}

__global__ __launch_bounds__(TPB, 4) void esl_moments(
    const float* __restrict__ probs, double* __restrict__ partials) {
  const int b = blockIdx.x >> 5;                   // batch
  const int blk = blockIdx.x & 31;                 // block within batch
  const int lane = threadIdx.x & 63;
  const int wid = threadIdx.x >> 6;
  const int wave_idx = blk * WAVES_PER_BLOCK + wid;  // wave within batch [0,128)
  const int y0 = wave_idx * ROWS_PER_WAVE;

  const float* __restrict__ p0 = probs + (size_t)b * 2 * NPIX;
  const float* __restrict__ p1 = p0 + NPIX;

  const double X = (double)(4 * lane);
  const double X2 = X * X, X3 = X2 * X, X4 = X2 * X2;

  double acc[NMOM];
#pragma unroll
  for (int i = 0; i < NMOM; ++i) acc[i] = 0.0;

  // 2-row software pipeline: row r+1's 8 loads are in flight while computing row r
  f32x4 a0[4], b0[4], a1[4], b1[4];
  load_row(reinterpret_cast<const f32x4*>(p0 + (size_t)y0 * W),
           reinterpret_cast<const f32x4*>(p1 + (size_t)y0 * W), lane, a0, b0);
#pragma unroll
  for (int r = 0; r < ROWS_PER_WAVE; r += 2) {
    {
      const int y = y0 + r + 1;
      load_row(reinterpret_cast<const f32x4*>(p0 + (size_t)y * W),
               reinterpret_cast<const f32x4*>(p1 + (size_t)y * W), lane, a1, b1);
    }
    compute_row(a0, b0, y0 + r, X, X2, X3, X4, acc);
    if (r + 2 < ROWS_PER_WAVE) {
      const int y = y0 + r + 2;
      load_row(reinterpret_cast<const f32x4*>(p0 + (size_t)y * W),
               reinterpret_cast<const f32x4*>(p1 + (size_t)y * W), lane, a0, b0);
    }
    compute_row(a1, b1, y0 + r + 1, X, X2, X3, X4, acc);
  }

  // wave shuffle reduce -> LDS across 4 waves -> per-block partial (no atomics)
  __shared__ double smem[WAVES_PER_BLOCK][NMOM];
#pragma unroll
  for (int i = 0; i < NMOM; ++i) {
    double v = acc[i];
    for (int o = 32; o > 0; o >>= 1) v += __shfl_down(v, o, 64);
    if (lane == 0) smem[wid][i] = v;
  }
  __syncthreads();
  if (threadIdx.x < NMOM) {
    double v = 0.0;
#pragma unroll
    for (int wv = 0; wv < WAVES_PER_BLOCK; ++wv) v += smem[wv][threadIdx.x];
    partials[blockIdx.x * 16 + threadIdx.x] = v;
  }
}

// 1024 threads: 2 threads per (batch, moment) slot, 16 partials each, shfl-pair
// combine, then per-batch covariance algebra on 32 lanes.
__global__ __launch_bounds__(1024) void esl_finalize(
    const double* __restrict__ partials, float* __restrict__ out) {
  __shared__ double M[BATCH][16];
  const int tid = threadIdx.x;
  const int slot = tid >> 1;            // (b,i) slot in [0,512)
  const int sub = tid & 1;
  const int b = slot >> 4;
  const int i = slot & 15;
  {
    double v = 0.0;
#pragma unroll
    for (int k = 0; k < BLOCKS_PER_BATCH / 2; ++k)
      v += partials[(b * BLOCKS_PER_BATCH + sub * (BLOCKS_PER_BATCH / 2) + k) * 16 + i];
    v += __shfl_down(v, 1, 64);         // pair partner is adjacent lane
    if (sub == 0) M[b][i] = v;
  }
  __syncthreads();

  double loss = 0.0, valid = 0.0;
  if (tid < BATCH) {
    const double* m = M[tid];
    const double n = m[0];
    const double n_safe = fmax(n, 2.0);
    const double ay = m[1] / n_safe;
    const double ax = m[2] / n_safe;
    const double ay2 = ay * ay, ay3 = ay2 * ay, ay4 = ay2 * ay2;
    const double ax2 = ax * ax, ax3 = ax2 * ax, ax4 = ax2 * ax2;

    const double C20 = m[3] - 2.0 * ay * m[1] + ay2 * n;
    const double C11 = m[4] - ay * m[2] - ax * m[1] + ay * ax * n;
    const double C02 = m[5] - 2.0 * ax * m[2] + ax2 * n;

    const double denom = fmax(n_safe - 1.0, 1.0);
    const double Syy = C20 / denom, Sxy = C11 / denom, Sxx = C02 / denom;
    const double a = Syy + 1e-6, d = Sxx + 1e-6, bb = Sxy;
    const double det = a * d - bb * bb;
    const double i00 = d / det, i11 = a / det, i01 = -bb / det;

    const double C40 = m[10] - 4.0 * ay * m[6] + 6.0 * ay2 * m[3]
                     - 4.0 * ay3 * m[1] + ay4 * n;
    const double C31 = m[11] - ax * m[6] - 3.0 * ay * m[7] + 3.0 * ay * ax * m[3]
                     + 3.0 * ay2 * m[4] - 3.0 * ay2 * ax * m[1]
                     - ay3 * m[2] + ay3 * ax * n;
    const double C22 = m[12] - 2.0 * ax * m[7] + ax2 * m[3] - 2.0 * ay * m[8]
                     + 4.0 * ay * ax * m[4] - 2.0 * ay * ax2 * m[1]
                     + ay2 * m[5] - 2.0 * ay2 * ax * m[2] + ay2 * ax2 * n;
    const double C13 = m[13] - ay * m[9] - 3.0 * ax * m[8] + 3.0 * ax * ay * m[5]
                     + 3.0 * ax2 * m[4] - 3.0 * ax2 * ay * m[2]
                     - ax3 * m[1] + ax3 * ay * n;
    const double C04 = m[14] - 4.0 * ax * m[9] + 6.0 * ax2 * m[5]
                     - 4.0 * ax3 * m[2] + ax4 * n;

    const double Swm  = i00 * C20 + 2.0 * i01 * C11 + i11 * C02;
    const double Swm2 = i00 * i00 * C40 + 4.0 * i00 * i01 * C31
                      + (2.0 * i00 * i11 + 4.0 * i01 * i01) * C22
                      + 4.0 * i01 * i11 * C13 + i11 * i11 * C04;
    const double loss_obj = (Swm2 - 2.0 * Swm + n) / n_safe;

    if (n >= 10.0) { valid = 1.0; loss = loss_obj; }
  }
  if (tid < 64) {
    for (int o = 32; o > 0; o >>= 1) {
      loss += __shfl_down(loss, o, 64);
      valid += __shfl_down(valid, o, 64);
    }
    if (tid == 0)
      out[0] = (float)((valid > 0.0) ? loss / fmax(valid, 1.0) : 0.0);
  }
}

extern "C" void kernel_launch(void* const* d_in, const int* in_sizes, int n_in,
                              void* d_out, int out_size, void* d_ws, size_t ws_size,
                              hipStream_t stream) {
  const float* probs = (const float*)d_in[0];
  float* out = (float*)d_out;
  double* partials = (double*)d_ws;                // 1024 * 16 * 8 B = 128 KB
  esl_moments<<<NBLOCKS, TPB, 0, stream>>>(probs, partials);
  esl_finalize<<<1, 1024, 0, stream>>>(partials, out);
}

// Round 5
// 59.458 us; speedup vs baseline: 1.8993x; 1.8993x over previous
//
#include <hip/hip_runtime.h>

// EllipticalShapeLoss: streaming pass computes raw moments M_pq = sum_mask y^p x^q
// (p+q<=4) per batch. Row-per-wave lane-contiguous nontemporal float4 loads with a
// 2-row software pipeline; per-block double partials to d_ws (no memset, no
// atomics, deterministic); parallel finalize kernel does the covariance algebra.
//
// NOTE: no __launch_bounds__ min-waves on esl_moments — forcing 4 waves/EU caps
// VGPR at 128 and spills the pipeline buffers to scratch (R4: 2x regression).

constexpr int BATCH = 32;
constexpr int H = 1024;
constexpr int W = 1024;
constexpr int NPIX = H * W;
constexpr int NMOM = 15;
constexpr int TPB = 256;                           // 4 waves per block
constexpr int WAVES_PER_BLOCK = TPB / 64;
constexpr int BLOCKS_PER_BATCH = 64;
constexpr int WAVES_PER_BATCH = BLOCKS_PER_BATCH * WAVES_PER_BLOCK;  // 256
constexpr int ROWS_PER_WAVE = H / WAVES_PER_BATCH;                   // 4
constexpr int NBLOCKS = BATCH * BLOCKS_PER_BATCH;                    // 2048

typedef float f32x4 __attribute__((ext_vector_type(4)));

// moment index -> (p,q):  0:(0,0) 1:(1,0) 2:(0,1) 3:(2,0) 4:(1,1) 5:(0,2)
// 6:(3,0) 7:(2,1) 8:(1,2) 9:(0,3) 10:(4,0) 11:(3,1) 12:(2,2) 13:(1,3) 14:(0,4)

__device__ __forceinline__ void load_row(const f32x4* __restrict__ r0,
                                         const f32x4* __restrict__ r1,
                                         int lane, f32x4* a, f32x4* b) {
#pragma unroll
  for (int j = 0; j < 4; ++j) a[j] = __builtin_nontemporal_load(r0 + j * 64 + lane);
#pragma unroll
  for (int j = 0; j < 4; ++j) b[j] = __builtin_nontemporal_load(r1 + j * 64 + lane);
}

__device__ __forceinline__ void compute_row(const f32x4* a, const f32x4* b, int y,
                                            const double X, const double X2,
                                            const double X3, const double X4,
                                            double* acc) {
  // masked power sums over v = 256j + t (compile-time literals)
  unsigned s0 = 0, s1 = 0, s2 = 0;
  unsigned long long s3 = 0, s4 = 0;
#pragma unroll
  for (int j = 0; j < 4; ++j) {
#pragma unroll
    for (int t = 0; t < 4; ++t) {
      const unsigned long long v = (unsigned long long)(256 * j + t);
      const bool m = b[j][t] > a[j][t];            // argmax==FG (ties -> class 0)
      s0 += m ? 1u : 0u;
      s1 += m ? (unsigned)v : 0u;
      s2 += m ? (unsigned)(v * v) : 0u;
      s3 += m ? v * v * v : 0ull;
      s4 += m ? v * v * v * v : 0ull;
    }
  }
  // binomial shift by X: T_q = sum_mask x^q over this thread's row pixels
  const double S0 = s0, S1 = s1, S2 = s2, S3 = (double)s3, S4 = (double)s4;
  const double T0 = S0;
  const double T1 = X * S0 + S1;
  const double T2 = X2 * S0 + 2.0 * X * S1 + S2;
  const double T3 = X3 * S0 + 3.0 * X2 * S1 + 3.0 * X * S2 + S3;
  const double T4 = X4 * S0 + 4.0 * X3 * S1 + 6.0 * X2 * S2 + 4.0 * X * S3 + S4;
  const double Y = (double)y;
  const double Y2 = Y * Y, Y3 = Y2 * Y, Y4 = Y2 * Y2;
  acc[0] += T0;
  acc[1] += Y * T0;
  acc[2] += T1;
  acc[3] += Y2 * T0;
  acc[4] += Y * T1;
  acc[5] += T2;
  acc[6] += Y3 * T0;
  acc[7] += Y2 * T1;
  acc[8] += Y * T2;
  acc[9] += T3;
  acc[10] += Y4 * T0;
  acc[11] += Y3 * T1;
  acc[12] += Y2 * T2;
  acc[13] += Y * T3;
  acc[14] += T4;
}

__global__ __launch_bounds__(TPB) void esl_moments(
    const float* __restrict__ probs, double* __restrict__ partials) {
  const int b = blockIdx.x / BLOCKS_PER_BATCH;
  const int blk = blockIdx.x % BLOCKS_PER_BATCH;
  const int lane = threadIdx.x & 63;
  const int wid = threadIdx.x >> 6;
  const int wave_idx = blk * WAVES_PER_BLOCK + wid;  // wave within batch
  const int y0 = wave_idx * ROWS_PER_WAVE;

  const float* __restrict__ p0 = probs + (size_t)b * 2 * NPIX;
  const float* __restrict__ p1 = p0 + NPIX;

  const double X = (double)(4 * lane);
  const double X2 = X * X, X3 = X2 * X, X4 = X2 * X2;

  double acc[NMOM];
#pragma unroll
  for (int i = 0; i < NMOM; ++i) acc[i] = 0.0;

  // 2-row software pipeline: row r+1's 8 loads are in flight while computing row r
  f32x4 a0[4], b0[4], a1[4], b1[4];
  load_row(reinterpret_cast<const f32x4*>(p0 + (size_t)y0 * W),
           reinterpret_cast<const f32x4*>(p1 + (size_t)y0 * W), lane, a0, b0);
#pragma unroll
  for (int r = 0; r < ROWS_PER_WAVE; r += 2) {
    {
      const int y = y0 + r + 1;
      load_row(reinterpret_cast<const f32x4*>(p0 + (size_t)y * W),
               reinterpret_cast<const f32x4*>(p1 + (size_t)y * W), lane, a1, b1);
    }
    compute_row(a0, b0, y0 + r, X, X2, X3, X4, acc);
    if (r + 2 < ROWS_PER_WAVE) {
      const int y = y0 + r + 2;
      load_row(reinterpret_cast<const f32x4*>(p0 + (size_t)y * W),
               reinterpret_cast<const f32x4*>(p1 + (size_t)y * W), lane, a0, b0);
    }
    compute_row(a1, b1, y0 + r + 1, X, X2, X3, X4, acc);
  }

  // wave shuffle reduce -> LDS across 4 waves -> per-block partial (no atomics)
  __shared__ double smem[WAVES_PER_BLOCK][NMOM];
#pragma unroll
  for (int i = 0; i < NMOM; ++i) {
    double v = acc[i];
    for (int o = 32; o > 0; o >>= 1) v += __shfl_down(v, o, 64);
    if (lane == 0) smem[wid][i] = v;
  }
  __syncthreads();
  if (threadIdx.x < NMOM) {
    double v = 0.0;
#pragma unroll
    for (int wv = 0; wv < WAVES_PER_BLOCK; ++wv) v += smem[wv][threadIdx.x];
    partials[blockIdx.x * 16 + threadIdx.x] = v;
  }
}

// 1024 threads: 2 threads per (batch, moment) slot, 32 partials each, shfl-pair
// combine, then per-batch covariance algebra on 32 lanes.
__global__ __launch_bounds__(1024) void esl_finalize(
    const double* __restrict__ partials, float* __restrict__ out) {
  __shared__ double M[BATCH][16];
  const int tid = threadIdx.x;
  const int slot = tid >> 1;            // (b,i) slot in [0,512)
  const int sub = tid & 1;
  const int b = slot >> 4;
  const int i = slot & 15;
  {
    double v = 0.0;
#pragma unroll
    for (int k = 0; k < BLOCKS_PER_BATCH / 2; ++k)
      v += partials[(b * BLOCKS_PER_BATCH + sub * (BLOCKS_PER_BATCH / 2) + k) * 16 + i];
    v += __shfl_down(v, 1, 64);         // pair partner is adjacent lane
    if (sub == 0) M[b][i] = v;
  }
  __syncthreads();

  double loss = 0.0, valid = 0.0;
  if (tid < BATCH) {
    const double* m = M[tid];
    const double n = m[0];
    const double n_safe = fmax(n, 2.0);
    const double ay = m[1] / n_safe;
    const double ax = m[2] / n_safe;
    const double ay2 = ay * ay, ay3 = ay2 * ay, ay4 = ay2 * ay2;
    const double ax2 = ax * ax, ax3 = ax2 * ax, ax4 = ax2 * ax2;

    const double C20 = m[3] - 2.0 * ay * m[1] + ay2 * n;
    const double C11 = m[4] - ay * m[2] - ax * m[1] + ay * ax * n;
    const double C02 = m[5] - 2.0 * ax * m[2] + ax2 * n;

    const double denom = fmax(n_safe - 1.0, 1.0);
    const double Syy = C20 / denom, Sxy = C11 / denom, Sxx = C02 / denom;
    const double a = Syy + 1e-6, d = Sxx + 1e-6, bb = Sxy;
    const double det = a * d - bb * bb;
    const double i00 = d / det, i11 = a / det, i01 = -bb / det;

    const double C40 = m[10] - 4.0 * ay * m[6] + 6.0 * ay2 * m[3]
                     - 4.0 * ay3 * m[1] + ay4 * n;
    const double C31 = m[11] - ax * m[6] - 3.0 * ay * m[7] + 3.0 * ay * ax * m[3]
                     + 3.0 * ay2 * m[4] - 3.0 * ay2 * ax * m[1]
                     - ay3 * m[2] + ay3 * ax * n;
    const double C22 = m[12] - 2.0 * ax * m[7] + ax2 * m[3] - 2.0 * ay * m[8]
                     + 4.0 * ay * ax * m[4] - 2.0 * ay * ax2 * m[1]
                     + ay2 * m[5] - 2.0 * ay2 * ax * m[2] + ay2 * ax2 * n;
    const double C13 = m[13] - ay * m[9] - 3.0 * ax * m[8] + 3.0 * ax * ay * m[5]
                     + 3.0 * ax2 * m[4] - 3.0 * ax2 * ay * m[2]
                     - ax3 * m[1] + ax3 * ay * n;
    const double C04 = m[14] - 4.0 * ax * m[9] + 6.0 * ax2 * m[5]
                     - 4.0 * ax3 * m[2] + ax4 * n;

    const double Swm  = i00 * C20 + 2.0 * i01 * C11 + i11 * C02;
    const double Swm2 = i00 * i00 * C40 + 4.0 * i00 * i01 * C31
                      + (2.0 * i00 * i11 + 4.0 * i01 * i01) * C22
                      + 4.0 * i01 * i11 * C13 + i11 * i11 * C04;
    const double loss_obj = (Swm2 - 2.0 * Swm + n) / n_safe;

    if (n >= 10.0) { valid = 1.0; loss = loss_obj; }
  }
  if (tid < 64) {
    for (int o = 32; o > 0; o >>= 1) {
      loss += __shfl_down(loss, o, 64);
      valid += __shfl_down(valid, o, 64);
    }
    if (tid == 0)
      out[0] = (float)((valid > 0.0) ? loss / fmax(valid, 1.0) : 0.0);
  }
}

extern "C" void kernel_launch(void* const* d_in, const int* in_sizes, int n_in,
                              void* d_out, int out_size, void* d_ws, size_t ws_size,
                              hipStream_t stream) {
  const float* probs = (const float*)d_in[0];
  float* out = (float*)d_out;
  double* partials = (double*)d_ws;                // 2048 * 16 * 8 B = 256 KB
  esl_moments<<<NBLOCKS, TPB, 0, stream>>>(probs, partials);
  esl_finalize<<<1, 1024, 0, stream>>>(partials, out);
}

// Round 6
// 56.166 us; speedup vs baseline: 2.0107x; 1.0586x over previous
//
#include <hip/hip_runtime.h>

// EllipticalShapeLoss: streaming pass computes raw moments M_pq = sum_mask y^p x^q
// (p+q<=4) per batch. Row-per-wave lane-contiguous nontemporal float4 loads with a
// 2-row software pipeline; per-block double partials to d_ws (no memset, no
// atomics, deterministic); small finalize kernel does the covariance algebra.
//
// Config notes (measured):
//  - R4: __launch_bounds__(256,4) caps VGPR at 128 -> spills pipeline buffers to
//    scratch -> 2x regression. Leave the allocator unbounded.
//  - R2/R3/R5 (57.7/56.1/59.5 us) show the harness noise band is ~+-3 us; this
//    file is the best-measured R3 configuration.

constexpr int BATCH = 32;
constexpr int H = 1024;
constexpr int W = 1024;
constexpr int NPIX = H * W;
constexpr int NMOM = 15;
constexpr int TPB = 256;                           // 4 waves per block
constexpr int WAVES_PER_BLOCK = TPB / 64;
constexpr int BLOCKS_PER_BATCH = 64;
constexpr int WAVES_PER_BATCH = BLOCKS_PER_BATCH * WAVES_PER_BLOCK;  // 256
constexpr int ROWS_PER_WAVE = H / WAVES_PER_BATCH;                   // 4
constexpr int NBLOCKS = BATCH * BLOCKS_PER_BATCH;                    // 2048

typedef float f32x4 __attribute__((ext_vector_type(4)));

// moment index -> (p,q):  0:(0,0) 1:(1,0) 2:(0,1) 3:(2,0) 4:(1,1) 5:(0,2)
// 6:(3,0) 7:(2,1) 8:(1,2) 9:(0,3) 10:(4,0) 11:(3,1) 12:(2,2) 13:(1,3) 14:(0,4)

__device__ __forceinline__ void load_row(const f32x4* __restrict__ r0,
                                         const f32x4* __restrict__ r1,
                                         int lane, f32x4* a, f32x4* b) {
#pragma unroll
  for (int j = 0; j < 4; ++j) a[j] = __builtin_nontemporal_load(r0 + j * 64 + lane);
#pragma unroll
  for (int j = 0; j < 4; ++j) b[j] = __builtin_nontemporal_load(r1 + j * 64 + lane);
}

__device__ __forceinline__ void compute_row(const f32x4* a, const f32x4* b, int y,
                                            const double X, const double X2,
                                            const double X3, const double X4,
                                            double* acc) {
  // masked power sums over v = 256j + t (compile-time literals)
  unsigned s0 = 0, s1 = 0, s2 = 0;
  unsigned long long s3 = 0, s4 = 0;
#pragma unroll
  for (int j = 0; j < 4; ++j) {
#pragma unroll
    for (int t = 0; t < 4; ++t) {
      const unsigned long long v = (unsigned long long)(256 * j + t);
      const bool m = b[j][t] > a[j][t];            // argmax==FG (ties -> class 0)
      s0 += m ? 1u : 0u;
      s1 += m ? (unsigned)v : 0u;
      s2 += m ? (unsigned)(v * v) : 0u;
      s3 += m ? v * v * v : 0ull;
      s4 += m ? v * v * v * v : 0ull;
    }
  }
  // binomial shift by X: T_q = sum_mask x^q over this thread's row pixels
  const double S0 = s0, S1 = s1, S2 = s2, S3 = (double)s3, S4 = (double)s4;
  const double T0 = S0;
  const double T1 = X * S0 + S1;
  const double T2 = X2 * S0 + 2.0 * X * S1 + S2;
  const double T3 = X3 * S0 + 3.0 * X2 * S1 + 3.0 * X * S2 + S3;
  const double T4 = X4 * S0 + 4.0 * X3 * S1 + 6.0 * X2 * S2 + 4.0 * X * S3 + S4;
  const double Y = (double)y;
  const double Y2 = Y * Y, Y3 = Y2 * Y, Y4 = Y2 * Y2;
  acc[0] += T0;
  acc[1] += Y * T0;
  acc[2] += T1;
  acc[3] += Y2 * T0;
  acc[4] += Y * T1;
  acc[5] += T2;
  acc[6] += Y3 * T0;
  acc[7] += Y2 * T1;
  acc[8] += Y * T2;
  acc[9] += T3;
  acc[10] += Y4 * T0;
  acc[11] += Y3 * T1;
  acc[12] += Y2 * T2;
  acc[13] += Y * T3;
  acc[14] += T4;
}

__global__ __launch_bounds__(TPB) void esl_moments(
    const float* __restrict__ probs, double* __restrict__ partials) {
  const int b = blockIdx.x / BLOCKS_PER_BATCH;
  const int blk = blockIdx.x % BLOCKS_PER_BATCH;
  const int lane = threadIdx.x & 63;
  const int wid = threadIdx.x >> 6;
  const int wave_idx = blk * WAVES_PER_BLOCK + wid;  // wave within batch
  const int y0 = wave_idx * ROWS_PER_WAVE;

  const float* __restrict__ p0 = probs + (size_t)b * 2 * NPIX;
  const float* __restrict__ p1 = p0 + NPIX;

  const double X = (double)(4 * lane);
  const double X2 = X * X, X3 = X2 * X, X4 = X2 * X2;

  double acc[NMOM];
#pragma unroll
  for (int i = 0; i < NMOM; ++i) acc[i] = 0.0;

  // 2-row software pipeline: row r+1's 8 loads are in flight while computing row r
  f32x4 a0[4], b0[4], a1[4], b1[4];
  load_row(reinterpret_cast<const f32x4*>(p0 + (size_t)y0 * W),
           reinterpret_cast<const f32x4*>(p1 + (size_t)y0 * W), lane, a0, b0);
#pragma unroll
  for (int r = 0; r < ROWS_PER_WAVE; r += 2) {
    {
      const int y = y0 + r + 1;
      load_row(reinterpret_cast<const f32x4*>(p0 + (size_t)y * W),
               reinterpret_cast<const f32x4*>(p1 + (size_t)y * W), lane, a1, b1);
    }
    compute_row(a0, b0, y0 + r, X, X2, X3, X4, acc);
    if (r + 2 < ROWS_PER_WAVE) {
      const int y = y0 + r + 2;
      load_row(reinterpret_cast<const f32x4*>(p0 + (size_t)y * W),
               reinterpret_cast<const f32x4*>(p1 + (size_t)y * W), lane, a0, b0);
    }
    compute_row(a1, b1, y0 + r + 1, X, X2, X3, X4, acc);
  }

  // wave shuffle reduce -> LDS across 4 waves -> per-block partial (no atomics)
  __shared__ double smem[WAVES_PER_BLOCK][NMOM];
#pragma unroll
  for (int i = 0; i < NMOM; ++i) {
    double v = acc[i];
    for (int o = 32; o > 0; o >>= 1) v += __shfl_down(v, o, 64);
    if (lane == 0) smem[wid][i] = v;
  }
  __syncthreads();
  if (threadIdx.x < NMOM) {
    double v = 0.0;
#pragma unroll
    for (int wv = 0; wv < WAVES_PER_BLOCK; ++wv) v += smem[wv][threadIdx.x];
    partials[blockIdx.x * 16 + threadIdx.x] = v;
  }
}

__global__ __launch_bounds__(512) void esl_finalize(
    const double* __restrict__ partials, float* __restrict__ out) {
  __shared__ double M[BATCH][16];
  __shared__ double red[2];
  const int tid = threadIdx.x;
  const int b = tid >> 4;
  const int i = tid & 15;
  if (i < NMOM) {
    double v = 0.0;
#pragma unroll
    for (int k = 0; k < BLOCKS_PER_BATCH; ++k)
      v += partials[(b * BLOCKS_PER_BATCH + k) * 16 + i];
    M[b][i] = v;
  }
  __syncthreads();

  double loss = 0.0, valid = 0.0;
  if (tid < BATCH) {
    const double* m = M[tid];
    const double n = m[0];
    const double n_safe = fmax(n, 2.0);
    const double ay = m[1] / n_safe;
    const double ax = m[2] / n_safe;
    const double ay2 = ay * ay, ay3 = ay2 * ay, ay4 = ay2 * ay2;
    const double ax2 = ax * ax, ax3 = ax2 * ax, ax4 = ax2 * ax2;

    const double C20 = m[3] - 2.0 * ay * m[1] + ay2 * n;
    const double C11 = m[4] - ay * m[2] - ax * m[1] + ay * ax * n;
    const double C02 = m[5] - 2.0 * ax * m[2] + ax2 * n;

    const double denom = fmax(n_safe - 1.0, 1.0);
    const double Syy = C20 / denom, Sxy = C11 / denom, Sxx = C02 / denom;
    const double a = Syy + 1e-6, d = Sxx + 1e-6, bb = Sxy;
    const double det = a * d - bb * bb;
    const double i00 = d / det, i11 = a / det, i01 = -bb / det;

    const double C40 = m[10] - 4.0 * ay * m[6] + 6.0 * ay2 * m[3]
                     - 4.0 * ay3 * m[1] + ay4 * n;
    const double C31 = m[11] - ax * m[6] - 3.0 * ay * m[7] + 3.0 * ay * ax * m[3]
                     + 3.0 * ay2 * m[4] - 3.0 * ay2 * ax * m[1]
                     - ay3 * m[2] + ay3 * ax * n;
    const double C22 = m[12] - 2.0 * ax * m[7] + ax2 * m[3] - 2.0 * ay * m[8]
                     + 4.0 * ay * ax * m[4] - 2.0 * ay * ax2 * m[1]
                     + ay2 * m[5] - 2.0 * ay2 * ax * m[2] + ay2 * ax2 * n;
    const double C13 = m[13] - ay * m[9] - 3.0 * ax * m[8] + 3.0 * ax * ay * m[5]
                     + 3.0 * ax2 * m[4] - 3.0 * ax2 * ay * m[2]
                     - ax3 * m[1] + ax3 * ay * n;
    const double C04 = m[14] - 4.0 * ax * m[9] + 6.0 * ax2 * m[5]
                     - 4.0 * ax3 * m[2] + ax4 * n;

    const double Swm  = i00 * C20 + 2.0 * i01 * C11 + i11 * C02;
    const double Swm2 = i00 * i00 * C40 + 4.0 * i00 * i01 * C31
                      + (2.0 * i00 * i11 + 4.0 * i01 * i01) * C22
                      + 4.0 * i01 * i11 * C13 + i11 * i11 * C04;
    const double loss_obj = (Swm2 - 2.0 * Swm + n) / n_safe;

    if (n >= 10.0) { valid = 1.0; loss = loss_obj; }
  }
  if (tid < 64) {
    for (int o = 32; o > 0; o >>= 1) {
      loss += __shfl_down(loss, o, 64);
      valid += __shfl_down(valid, o, 64);
    }
    if (tid == 0) {
      red[0] = loss; red[1] = valid;
      out[0] = (float)((red[1] > 0.0) ? red[0] / fmax(red[1], 1.0) : 0.0);
    }
  }
}

extern "C" void kernel_launch(void* const* d_in, const int* in_sizes, int n_in,
                              void* d_out, int out_size, void* d_ws, size_t ws_size,
                              hipStream_t stream) {
  const float* probs = (const float*)d_in[0];
  float* out = (float*)d_out;
  double* partials = (double*)d_ws;                // 2048 * 16 * 8 B = 256 KB
  esl_moments<<<NBLOCKS, TPB, 0, stream>>>(probs, partials);
  esl_finalize<<<1, 512, 0, stream>>>(partials, out);
}